// Round 13
// baseline (207.575 us; speedup 1.0000x reference)
//
#include <hip/hip_runtime.h>
#include <hip/hip_fp16.h>

#define BB 2
#define NN 1024
#define MM 1024
#define DD 256
#define HH 128
#define C2LE 2.8853900817779268f       // 2*log2(e)
#define NEG2LOG2E -2.8853900817779268f // -2*log2(e)
#define SHIFT_C -4.3280860f            // -3*log2(e): P = e^{s-3}, softmax-invariant
#define REPS_SC 3                      // attribution: x3 scores
#define REPS_ATT 5                     // attribution: x5 attend

typedef float v2f __attribute__((ext_vector_type(2)));
typedef float v4f __attribute__((ext_vector_type(4)));
typedef _Float16 h8 __attribute__((ext_vector_type(8)));

// ---- Kernel 1: blocks <512: e = exp2(C*(x@W+bias)) -> EaT (A, transposed) /
// Eb (B, row-major). blocks >=512: KT_hi/lo[b][d][m] = f16 split of key^T.
__global__ __launch_bounds__(256) void proj_conv_kernel(
    const float* __restrict__ query, const float* __restrict__ key,
    const float* __restrict__ Wa_w, const float* __restrict__ Wa_b,
    const float* __restrict__ Wb_w, const float* __restrict__ Wb_b,
    float* __restrict__ EaT, float* __restrict__ Eb,
    __half* __restrict__ KT_hi, __half* __restrict__ KT_lo) {
    __shared__ float rows[8][DD];
    __shared__ float partial[8][HH];
    __shared__ float t[64][65];
    const int tid = threadIdx.x;

    if (blockIdx.x >= 512) {  // ---- convert branch
        const int cid = blockIdx.x - 512;
        const int m0 = (cid & 15) * 64, d0 = ((cid >> 4) & 3) * 64, b = cid >> 6;
        for (int i = tid; i < 1024; i += 256) {
            const int r = i >> 4, c4 = i & 15;
            const float4 v =
                *(const float4*)&key[((size_t)(b * MM + m0 + r)) * DD + d0 + c4 * 4];
            t[r][c4 * 4 + 0] = v.x; t[r][c4 * 4 + 1] = v.y;
            t[r][c4 * 4 + 2] = v.z; t[r][c4 * 4 + 3] = v.w;
        }
        __syncthreads();
        for (int i = tid; i < 4096; i += 256) {
            const int dr = i >> 6, mc = i & 63;
            const float f = t[mc][dr];
            const __half hi = __float2half(f);
            const __half lo = __float2half(f - __half2float(hi));
            const size_t o = ((size_t)(b * DD + d0 + dr)) * MM + m0 + mc;
            KT_hi[o] = hi;
            KT_lo[o] = lo;
        }
        return;
    }

    const int rb = blockIdx.x * 8;
    const bool isA = rb < BB * NN;
    const float* in = isA ? query : key;
    const float* W  = isA ? Wa_w : Wb_w;
    const float* bias = isA ? Wa_b : Wb_b;
    const int base = isA ? rb : rb - BB * NN;

    const float4* in4 = (const float4*)(in + (size_t)base * DD);
    float4* rows4 = (float4*)rows;
    rows4[tid] = in4[tid];
    rows4[tid + 256] = in4[tid + 256];
    __syncthreads();

    const int h = tid & 127, half = tid >> 7;
    const int d0 = half * 128;
    float acc[8] = {};
    for (int d = d0; d < d0 + 128; d += 4) {
        const float w0 = W[(d + 0) * HH + h];
        const float w1 = W[(d + 1) * HH + h];
        const float w2 = W[(d + 2) * HH + h];
        const float w3 = W[(d + 3) * HH + h];
#pragma unroll
        for (int r = 0; r < 8; ++r) {
            const float4 rv = *(const float4*)&rows[r][d];
            acc[r] = fmaf(rv.x, w0, fmaf(rv.y, w1, fmaf(rv.z, w2, fmaf(rv.w, w3, acc[r]))));
        }
    }
    if (half) {
#pragma unroll
        for (int r = 0; r < 8; ++r) partial[r][h] = acc[r];
    }
    __syncthreads();
    if (!half) {
        const float bv = bias[h];
        float ev[8];
#pragma unroll
        for (int r = 0; r < 8; ++r)
            ev[r] = __builtin_amdgcn_exp2f(C2LE * (acc[r] + partial[r][h] + bv));
        if (isA) {
            const int bq = base >> 10, nb = base & (NN - 1);
            float* dst = EaT + ((size_t)(bq * HH + h)) * NN + nb;
            *(float4*)dst = *(float4*)&ev[0];
            *(float4*)(dst + 4) = *(float4*)&ev[4];
        } else {
#pragma unroll
            for (int r = 0; r < 8; ++r)
                Eb[(size_t)(base + r) * HH + h] = ev[r];
        }
    }
}

// ---- Kernel 2 v2: Ph = f16(exp(-2*sum_h v_h/(Ea*Eb+1) - 3)) + psum.
// Tile 32n x 128m (mt=2 per lane), h in 2 chunks of 64. a register-cached
// across the mt loop -> per-h4 fixed costs amortized over 2x terms.
__global__ __launch_bounds__(256) void scores_kernel(
    const float* __restrict__ EaT, const float* __restrict__ Eb,
    const float* __restrict__ v_w, __half* __restrict__ Ph,
    float* __restrict__ psum) {
    __shared__ float b_s[128 * 64];  // 32KB, swizzled: slot = h4 ^ (r&15)
    __shared__ float a_s[64 * 32];   // 8KB, [h][n]
    const int tid = threadIdx.x;
    const int m0 = blockIdx.x * 128, n0 = blockIdx.y * 32, b = blockIdx.z;
    const int lane = tid & 63;
    const int ng = __builtin_amdgcn_readfirstlane(threadIdx.x >> 6);
    const int skey = lane & 15;

#pragma unroll 1
    for (int rep = 0; rep < REPS_SC; ++rep) {
        asm volatile("" ::: "memory");
        v2f acc[2][4] = {};  // [mt][np]
        for (int hc = 0; hc < 2; ++hc) {
            __syncthreads();
            for (int i = tid; i < 128 * 16; i += 256) {
                const int r = i >> 4, h4 = i & 15;
                *(float4*)&b_s[r * 64 + ((h4 ^ (r & 15)) << 2)] =
                    *(const float4*)&Eb[((size_t)(b * MM + m0 + r)) * HH + hc * 64 + h4 * 4];
            }
            for (int i = tid; i < 64 * 8; i += 256) {
                const int hh = i >> 3, n4 = i & 7;
                *(float4*)&a_s[hh * 32 + n4 * 4] =
                    *(const float4*)&EaT[((size_t)(b * HH + hc * 64 + hh)) * NN + n0 + n4 * 4];
            }
            __syncthreads();

#pragma unroll 4
            for (int h4 = 0; h4 < 16; ++h4) {
                const float4 w4 = *(const float4*)&v_w[hc * 64 + h4 * 4];  // uniform
                const float* ap = &a_s[h4 * 4 * 32 + ng * 8];
                v2f A0[4], A1[4], A2[4], A3[4];
#pragma unroll
                for (int np = 0; np < 4; ++np) {
                    A0[np] = *(const v2f*)&ap[0 * 32 + np * 2];
                    A1[np] = *(const v2f*)&ap[1 * 32 + np * 2];
                    A2[np] = *(const v2f*)&ap[2 * 32 + np * 2];
                    A3[np] = *(const v2f*)&ap[3 * 32 + np * 2];
                }
#pragma unroll
                for (int mt = 0; mt < 2; ++mt) {
                    const float4 b4 = *(const float4*)
                        &b_s[(mt * 64 + lane) * 64 + ((h4 ^ skey) << 2)];
#pragma unroll
                    for (int np = 0; np < 4; ++np) {
                        const v2f u0 = A0[np] * b4.x + 1.0f;
                        const v2f u1 = A1[np] * b4.y + 1.0f;
                        const v2f u2 = A2[np] * b4.z + 1.0f;
                        const v2f u3 = A3[np] * b4.w + 1.0f;
                        const v2f p01 = u0 * u1, p23 = u2 * u3;
                        const v2f An = w4.x * u1 + w4.y * u0;
                        const v2f Bn = w4.z * u3 + w4.w * u2;
                        const v2f num = An * p23 + Bn * p01;
                        const v2f Pp = p01 * p23;
                        v2f r2;
                        r2.x = __builtin_amdgcn_rcpf(Pp.x);
                        r2.y = __builtin_amdgcn_rcpf(Pp.y);
                        acc[mt][np] = num * r2 + acc[mt][np];
                    }
                }
            }
        }

        const size_t prow = ((size_t)b * NN + n0 + ng * 8) * MM + m0 + lane;
#pragma unroll
        for (int j = 0; j < 8; ++j) {
#pragma unroll
            for (int mt = 0; mt < 2; ++mt) {
                const float pv = __builtin_amdgcn_exp2f(
                    fmaf(acc[mt][j >> 1][j & 1], NEG2LOG2E, SHIFT_C));
                Ph[prow + (size_t)j * MM + mt * 64] = __float2half(pv);
                float s = pv;
#pragma unroll
                for (int o = 32; o > 0; o >>= 1) s += __shfl_xor(s, o);
                if (lane == 0)
                    psum[((size_t)(m0 / 64 + mt) * BB + b) * NN + n0 + ng * 8 + j] = s;
            }
        }
    }
}

// ---- Kernel 3 v3: partial[kh] = P[:, kh-half] @ K[kh-half, :] via MFMA.
// 1024 blocks, 4 waves (16n x 16d), k=512, depth-2 prefetch, XCD swizzle.
__global__ __launch_bounds__(256) void attend_kernel(
    const __half* __restrict__ Ph, const __half* __restrict__ KT_hi,
    const __half* __restrict__ KT_lo, float* __restrict__ partial) {
    const int bid = blockIdx.x;
    const int xcd = bid & 7, c = bid >> 3;
    const int dt = c & 7, kh = (c >> 3) & 1, nb = c >> 4;
    const int ncombo = xcd * 8 + nb;
    const int b = ncombo >> 5, nt = ncombo & 31;
    const int n0 = nt * 32, d0 = dt * 32, m0 = kh * 512;

    const int tid = threadIdx.x;
    const int wave = __builtin_amdgcn_readfirstlane(threadIdx.x >> 6);
    const int lane = tid & 63;
    const int nh = wave >> 1, dh = wave & 1;
    const int row16 = lane & 15, kg = lane >> 4;

    const h8* A = (const h8*)(Ph + ((size_t)(b * NN + n0 + nh * 16 + row16)) * MM + m0 + kg * 8);
    const h8* BH = (const h8*)(KT_hi + ((size_t)(b * DD + d0 + dh * 16 + row16)) * MM + m0 + kg * 8);
    const h8* BL = (const h8*)(KT_lo + ((size_t)(b * DD + d0 + dh * 16 + row16)) * MM + m0 + kg * 8);

#pragma unroll 1
    for (int rep = 0; rep < REPS_ATT; ++rep) {
        asm volatile("" ::: "memory");
        v4f ch = {0.f, 0.f, 0.f, 0.f}, cl = ch;
        h8 a0 = A[0], bh0 = BH[0], bl0 = BL[0];
        h8 a1 = A[4], bh1 = BH[4], bl1 = BL[4];
#pragma unroll 1
        for (int it = 0; it < 14; it += 2) {
            const h8 a2 = A[(it + 2) * 4];
            const h8 bh2 = BH[(it + 2) * 4];
            const h8 bl2 = BL[(it + 2) * 4];
            const h8 a3 = A[(it + 3) * 4];
            const h8 bh3 = BH[(it + 3) * 4];
            const h8 bl3 = BL[(it + 3) * 4];
            ch = __builtin_amdgcn_mfma_f32_16x16x32_f16(a0, bh0, ch, 0, 0, 0);
            cl = __builtin_amdgcn_mfma_f32_16x16x32_f16(a0, bl0, cl, 0, 0, 0);
            ch = __builtin_amdgcn_mfma_f32_16x16x32_f16(a1, bh1, ch, 0, 0, 0);
            cl = __builtin_amdgcn_mfma_f32_16x16x32_f16(a1, bl1, cl, 0, 0, 0);
            a0 = a2; bh0 = bh2; bl0 = bl2;
            a1 = a3; bh1 = bh3; bl1 = bl3;
        }
        ch = __builtin_amdgcn_mfma_f32_16x16x32_f16(a0, bh0, ch, 0, 0, 0);
        cl = __builtin_amdgcn_mfma_f32_16x16x32_f16(a0, bl0, cl, 0, 0, 0);
        ch = __builtin_amdgcn_mfma_f32_16x16x32_f16(a1, bh1, ch, 0, 0, 0);
        cl = __builtin_amdgcn_mfma_f32_16x16x32_f16(a1, bl1, cl, 0, 0, 0);

        float* pp = partial +
            (((size_t)kh * BB + b) * NN + n0 + nh * 16 + kg * 4) * DD + d0 + dh * 16 + row16;
#pragma unroll
        for (int r = 0; r < 4; ++r) pp[(size_t)r * DD] = ch[r] + cl[r];
    }
}

// ---- Kernel 4: out[b,n,d] = (partial[0]+partial[1]) / sum_q psum[q][b][n]
__global__ __launch_bounds__(256) void combine_kernel(
    const float* __restrict__ partial, const float* __restrict__ psum,
    float* __restrict__ out) {
    const int n = blockIdx.x, b = blockIdx.y, d = threadIdx.x;
    float s = 0.f;
#pragma unroll
    for (int q = 0; q < 16; ++q)
        s += psum[((size_t)q * BB + b) * NN + n];
    const size_t off = ((size_t)b * NN + n) * DD + d;
    const float a =
        partial[off] + partial[(size_t)BB * NN * DD + off];
    out[off] = a * __builtin_amdgcn_rcpf(s);
}

extern "C" void kernel_launch(void* const* d_in, const int* in_sizes, int n_in,
                              void* d_out, int out_size, void* d_ws, size_t ws_size,
                              hipStream_t stream) {
    const float* query = (const float*)d_in[0];
    const float* key   = (const float*)d_in[1];
    const float* Wa_w  = (const float*)d_in[2];
    const float* Wa_b  = (const float*)d_in[3];
    const float* Wb_w  = (const float*)d_in[4];
    const float* Wb_b  = (const float*)d_in[5];
    const float* v_w   = (const float*)d_in[6];
    float* out = (float*)d_out;

    float* ws = (float*)d_ws;
    float* EaT  = ws;                          // BB*HH*NN f32
    float* Eb   = EaT + BB * NN * HH;          // BB*MM*HH f32
    float* psum = Eb + BB * MM * HH;           // 16*BB*NN f32
    __half* Ph    = (__half*)(psum + 16 * BB * NN);   // BB*NN*MM f16
    __half* KT_hi = Ph + (size_t)BB * NN * MM;        // BB*DD*MM f16
    __half* KT_lo = KT_hi + (size_t)BB * DD * MM;     // BB*DD*MM f16
    float* partial = (float*)(KT_lo + (size_t)BB * DD * MM);  // 2*BB*NN*DD f32

    proj_conv_kernel<<<dim3(512 + 128), dim3(256), 0, stream>>>(
        query, key, Wa_w, Wa_b, Wb_w, Wb_b, EaT, Eb, KT_hi, KT_lo);
    scores_kernel<<<dim3(MM / 128, NN / 32, BB), dim3(256), 0, stream>>>(
        EaT, Eb, v_w, Ph, psum);
    attend_kernel<<<dim3(1024), dim3(256), 0, stream>>>(
        Ph, KT_hi, KT_lo, partial);
    combine_kernel<<<dim3(NN, BB), dim3(256), 0, stream>>>(
        partial, psum, out);
}

// Round 14
// 61.354 us; speedup vs baseline: 3.3833x; 3.3833x over previous
//
#include <hip/hip_runtime.h>
#include <hip/hip_fp16.h>

#define BB 2
#define NN 1024
#define MM 1024
#define DD 256
#define HH 128
#define C2LE 2.8853900817779268f       // 2*log2(e)
#define NEG2LOG2E -2.8853900817779268f // -2*log2(e)
#define SHIFT_C -4.3280860f            // -3*log2(e): P = e^{s-3}, softmax-invariant

typedef float v2f __attribute__((ext_vector_type(2)));
typedef float v4f __attribute__((ext_vector_type(4)));
typedef _Float16 h8 __attribute__((ext_vector_type(8)));

// ---- Kernel 1: blocks <512: e = exp2(C*(x@W+bias)) -> EaT (A, transposed) /
// Eb (B, row-major). blocks >=512: KT_hi/lo[b][d][m] = f16 split of key^T.
__global__ __launch_bounds__(256) void proj_conv_kernel(
    const float* __restrict__ query, const float* __restrict__ key,
    const float* __restrict__ Wa_w, const float* __restrict__ Wa_b,
    const float* __restrict__ Wb_w, const float* __restrict__ Wb_b,
    float* __restrict__ EaT, float* __restrict__ Eb,
    __half* __restrict__ KT_hi, __half* __restrict__ KT_lo) {
    __shared__ float rows[8][DD];
    __shared__ float partial[8][HH];
    __shared__ float t[64][65];
    const int tid = threadIdx.x;

    if (blockIdx.x >= 512) {  // ---- convert branch
        const int cid = blockIdx.x - 512;
        const int m0 = (cid & 15) * 64, d0 = ((cid >> 4) & 3) * 64, b = cid >> 6;
        for (int i = tid; i < 1024; i += 256) {
            const int r = i >> 4, c4 = i & 15;
            const float4 v =
                *(const float4*)&key[((size_t)(b * MM + m0 + r)) * DD + d0 + c4 * 4];
            t[r][c4 * 4 + 0] = v.x; t[r][c4 * 4 + 1] = v.y;
            t[r][c4 * 4 + 2] = v.z; t[r][c4 * 4 + 3] = v.w;
        }
        __syncthreads();
        for (int i = tid; i < 4096; i += 256) {
            const int dr = i >> 6, mc = i & 63;
            const float f = t[mc][dr];
            const __half hi = __float2half(f);
            const __half lo = __float2half(f - __half2float(hi));
            const size_t o = ((size_t)(b * DD + d0 + dr)) * MM + m0 + mc;
            KT_hi[o] = hi;
            KT_lo[o] = lo;
        }
        return;
    }

    const int rb = blockIdx.x * 8;
    const bool isA = rb < BB * NN;
    const float* in = isA ? query : key;
    const float* W  = isA ? Wa_w : Wb_w;
    const float* bias = isA ? Wa_b : Wb_b;
    const int base = isA ? rb : rb - BB * NN;

    const float4* in4 = (const float4*)(in + (size_t)base * DD);
    float4* rows4 = (float4*)rows;
    rows4[tid] = in4[tid];
    rows4[tid + 256] = in4[tid + 256];
    __syncthreads();

    const int h = tid & 127, half = tid >> 7;
    const int d0 = half * 128;
    float acc[8] = {};
    for (int d = d0; d < d0 + 128; d += 4) {
        const float w0 = W[(d + 0) * HH + h];
        const float w1 = W[(d + 1) * HH + h];
        const float w2 = W[(d + 2) * HH + h];
        const float w3 = W[(d + 3) * HH + h];
#pragma unroll
        for (int r = 0; r < 8; ++r) {
            const float4 rv = *(const float4*)&rows[r][d];
            acc[r] = fmaf(rv.x, w0, fmaf(rv.y, w1, fmaf(rv.z, w2, fmaf(rv.w, w3, acc[r]))));
        }
    }
    if (half) {
#pragma unroll
        for (int r = 0; r < 8; ++r) partial[r][h] = acc[r];
    }
    __syncthreads();
    if (!half) {
        const float bv = bias[h];
        float ev[8];
#pragma unroll
        for (int r = 0; r < 8; ++r)
            ev[r] = __builtin_amdgcn_exp2f(C2LE * (acc[r] + partial[r][h] + bv));
        if (isA) {
            const int bq = base >> 10, nb = base & (NN - 1);
            float* dst = EaT + ((size_t)(bq * HH + h)) * NN + nb;
            *(float4*)dst = *(float4*)&ev[0];
            *(float4*)(dst + 4) = *(float4*)&ev[4];
        } else {
#pragma unroll
            for (int r = 0; r < 8; ++r)
                Eb[(size_t)(base + r) * HH + h] = ev[r];
        }
    }
}

// ---- Kernel 2 v2: Ph = f16(exp(-2*sum_h v_h/(Ea*Eb+1) - 3)) + psum.
// Tile 32n x 128m (mt=2 per lane), h in 2 chunks of 64.
__global__ __launch_bounds__(256) void scores_kernel(
    const float* __restrict__ EaT, const float* __restrict__ Eb,
    const float* __restrict__ v_w, __half* __restrict__ Ph,
    float* __restrict__ psum) {
    __shared__ float b_s[128 * 64];  // 32KB, swizzled: slot = h4 ^ (r&15)
    __shared__ float a_s[64 * 32];   // 8KB, [h][n]
    const int tid = threadIdx.x;
    const int m0 = blockIdx.x * 128, n0 = blockIdx.y * 32, b = blockIdx.z;
    const int lane = tid & 63;
    const int ng = __builtin_amdgcn_readfirstlane(threadIdx.x >> 6);
    const int skey = lane & 15;

    v2f acc[2][4] = {};  // [mt][np]
    for (int hc = 0; hc < 2; ++hc) {
        __syncthreads();
        for (int i = tid; i < 128 * 16; i += 256) {
            const int r = i >> 4, h4 = i & 15;
            *(float4*)&b_s[r * 64 + ((h4 ^ (r & 15)) << 2)] =
                *(const float4*)&Eb[((size_t)(b * MM + m0 + r)) * HH + hc * 64 + h4 * 4];
        }
        for (int i = tid; i < 64 * 8; i += 256) {
            const int hh = i >> 3, n4 = i & 7;
            *(float4*)&a_s[hh * 32 + n4 * 4] =
                *(const float4*)&EaT[((size_t)(b * HH + hc * 64 + hh)) * NN + n0 + n4 * 4];
        }
        __syncthreads();

#pragma unroll 4
        for (int h4 = 0; h4 < 16; ++h4) {
            const float4 w4 = *(const float4*)&v_w[hc * 64 + h4 * 4];  // uniform
            const float* ap = &a_s[h4 * 4 * 32 + ng * 8];
            v2f A0[4], A1[4], A2[4], A3[4];
#pragma unroll
            for (int np = 0; np < 4; ++np) {
                A0[np] = *(const v2f*)&ap[0 * 32 + np * 2];
                A1[np] = *(const v2f*)&ap[1 * 32 + np * 2];
                A2[np] = *(const v2f*)&ap[2 * 32 + np * 2];
                A3[np] = *(const v2f*)&ap[3 * 32 + np * 2];
            }
#pragma unroll
            for (int mt = 0; mt < 2; ++mt) {
                const float4 b4 = *(const float4*)
                    &b_s[(mt * 64 + lane) * 64 + ((h4 ^ skey) << 2)];
#pragma unroll
                for (int np = 0; np < 4; ++np) {
                    const v2f u0 = A0[np] * b4.x + 1.0f;
                    const v2f u1 = A1[np] * b4.y + 1.0f;
                    const v2f u2 = A2[np] * b4.z + 1.0f;
                    const v2f u3 = A3[np] * b4.w + 1.0f;
                    const v2f p01 = u0 * u1, p23 = u2 * u3;
                    const v2f An = w4.x * u1 + w4.y * u0;
                    const v2f Bn = w4.z * u3 + w4.w * u2;
                    const v2f num = An * p23 + Bn * p01;
                    const v2f Pp = p01 * p23;
                    v2f r2;
                    r2.x = __builtin_amdgcn_rcpf(Pp.x);
                    r2.y = __builtin_amdgcn_rcpf(Pp.y);
                    acc[mt][np] = num * r2 + acc[mt][np];
                }
            }
        }
    }

    const size_t prow = ((size_t)b * NN + n0 + ng * 8) * MM + m0 + lane;
#pragma unroll
    for (int j = 0; j < 8; ++j) {
#pragma unroll
        for (int mt = 0; mt < 2; ++mt) {
            const float pv = __builtin_amdgcn_exp2f(
                fmaf(acc[mt][j >> 1][j & 1], NEG2LOG2E, SHIFT_C));
            Ph[prow + (size_t)j * MM + mt * 64] = __float2half(pv);
            float s = pv;
#pragma unroll
            for (int o = 32; o > 0; o >>= 1) s += __shfl_xor(s, o);
            if (lane == 0)
                psum[((size_t)(m0 / 64 + mt) * BB + b) * NN + n0 + ng * 8 + j] = s;
        }
    }
}

// ---- Kernel 3 v4: LDS-staged double-buffered MFMA GEMM (canonical).
// Block 64n x 64d, k-split 2 (m0=ks*512), 8 k-steps of 64. 512 threads
// reg-stage P/KT tiles in fragment order; waves MFMA from LDS.
// Grid 256: bid = nt*16 + g, g=(dt,ks,b) -> bid%8 groups same-KT blocks/XCD.
__global__ __launch_bounds__(512) void attend_kernel(
    const __half* __restrict__ Ph, const __half* __restrict__ KT_hi,
    const __half* __restrict__ KT_lo, float* __restrict__ partial) {
    __shared__ __align__(16) __half Ab[2][4096];  // 16KB
    __shared__ __align__(16) __half Bh[2][4096];  // 16KB
    __shared__ __align__(16) __half Bl[2][4096];  // 16KB

    const int bid = blockIdx.x;
    const int g = bid & 15, nt = bid >> 4;
    const int dt = g >> 2, ks = (g >> 1) & 1, b = g & 1;
    const int n0 = nt * 64, d0 = dt * 64, m0 = ks * 512;

    const int tid = threadIdx.x;
    const int lane = tid & 63;
    // staging decomposition: tid -> (t, kh, kg, row); LDS halfword off = tid*8
    const int srow = tid & 15, skg = (tid >> 4) & 3;
    const int ssub = tid >> 6, skh = ssub & 1, st = ssub >> 1;
    const int scol = m0 + skh * 32 + skg * 8;

    const __half* srcA = Ph    + ((size_t)(b * NN + n0 + st * 16 + srow)) * MM + scol;
    const __half* srcH = KT_hi + ((size_t)(b * DD + d0 + st * 16 + srow)) * MM + scol;
    const __half* srcL = KT_lo + ((size_t)(b * DD + d0 + st * 16 + srow)) * MM + scol;

    const int wave = __builtin_amdgcn_readfirstlane(threadIdx.x >> 6);
    const int t0 = (wave >> 2) * 2, td = wave & 3;  // 2 n-tiles, 1 d-tile

    v4f ch0 = {0.f, 0.f, 0.f, 0.f}, cl0 = ch0, ch1 = ch0, cl1 = ch0;

    h8 ra = *(const h8*)srcA;   // prologue loads (step 0)
    h8 rh = *(const h8*)srcH;
    h8 rl = *(const h8*)srcL;

    int cur = 0;
#pragma unroll 1
    for (int step = 0; step < 8; ++step) {
        *(h8*)&Ab[cur][tid * 8] = ra;
        *(h8*)&Bh[cur][tid * 8] = rh;
        *(h8*)&Bl[cur][tid * 8] = rl;
        if (step < 7) {  // issue next step's loads; latency hides under MFMA
            ra = *(const h8*)(srcA + (step + 1) * 64);
            rh = *(const h8*)(srcH + (step + 1) * 64);
            rl = *(const h8*)(srcL + (step + 1) * 64);
        }
        __syncthreads();
        const __half* A = Ab[cur];
        const __half* H = Bh[cur];
        const __half* L = Bl[cur];
        const h8 a00 = *(const h8*)&A[((t0 * 2 + 0) * 64 + lane) * 8];
        const h8 a01 = *(const h8*)&A[((t0 * 2 + 1) * 64 + lane) * 8];
        const h8 a10 = *(const h8*)&A[((t0 * 2 + 2) * 64 + lane) * 8];
        const h8 a11 = *(const h8*)&A[((t0 * 2 + 3) * 64 + lane) * 8];
        const h8 bh0 = *(const h8*)&H[((td * 2 + 0) * 64 + lane) * 8];
        const h8 bh1 = *(const h8*)&H[((td * 2 + 1) * 64 + lane) * 8];
        const h8 bl0 = *(const h8*)&L[((td * 2 + 0) * 64 + lane) * 8];
        const h8 bl1 = *(const h8*)&L[((td * 2 + 1) * 64 + lane) * 8];
        ch0 = __builtin_amdgcn_mfma_f32_16x16x32_f16(a00, bh0, ch0, 0, 0, 0);
        ch0 = __builtin_amdgcn_mfma_f32_16x16x32_f16(a01, bh1, ch0, 0, 0, 0);
        cl0 = __builtin_amdgcn_mfma_f32_16x16x32_f16(a00, bl0, cl0, 0, 0, 0);
        cl0 = __builtin_amdgcn_mfma_f32_16x16x32_f16(a01, bl1, cl0, 0, 0, 0);
        ch1 = __builtin_amdgcn_mfma_f32_16x16x32_f16(a10, bh0, ch1, 0, 0, 0);
        ch1 = __builtin_amdgcn_mfma_f32_16x16x32_f16(a11, bh1, ch1, 0, 0, 0);
        cl1 = __builtin_amdgcn_mfma_f32_16x16x32_f16(a10, bl0, cl1, 0, 0, 0);
        cl1 = __builtin_amdgcn_mfma_f32_16x16x32_f16(a11, bl1, cl1, 0, 0, 0);
        cur ^= 1;  // dbuf: next write goes to other buffer (1 barrier/step)
    }

    const int row16 = lane & 15, kg = lane >> 4;
    const v4f c0 = ch0 + cl0, c1 = ch1 + cl1;
    float* pp0 = partial +
        (((size_t)ks * BB + b) * NN + n0 + t0 * 16 + kg * 4) * DD + d0 + td * 16 + row16;
    float* pp1 = pp0 + (size_t)16 * DD;
#pragma unroll
    for (int r = 0; r < 4; ++r) pp0[(size_t)r * DD] = c0[r];
#pragma unroll
    for (int r = 0; r < 4; ++r) pp1[(size_t)r * DD] = c1[r];
}

// ---- Kernel 4: out[b,n,d] = (partial[0]+partial[1]) / sum_q psum[q][b][n]
__global__ __launch_bounds__(256) void combine_kernel(
    const float* __restrict__ partial, const float* __restrict__ psum,
    float* __restrict__ out) {
    const int n = blockIdx.x, b = blockIdx.y, d = threadIdx.x;
    float s = 0.f;
#pragma unroll
    for (int q = 0; q < 16; ++q)
        s += psum[((size_t)q * BB + b) * NN + n];
    const size_t off = ((size_t)b * NN + n) * DD + d;
    const float a = partial[off] + partial[(size_t)BB * NN * DD + off];
    out[off] = a * __builtin_amdgcn_rcpf(s);
}

extern "C" void kernel_launch(void* const* d_in, const int* in_sizes, int n_in,
                              void* d_out, int out_size, void* d_ws, size_t ws_size,
                              hipStream_t stream) {
    const float* query = (const float*)d_in[0];
    const float* key   = (const float*)d_in[1];
    const float* Wa_w  = (const float*)d_in[2];
    const float* Wa_b  = (const float*)d_in[3];
    const float* Wb_w  = (const float*)d_in[4];
    const float* Wb_b  = (const float*)d_in[5];
    const float* v_w   = (const float*)d_in[6];
    float* out = (float*)d_out;

    float* ws = (float*)d_ws;
    float* EaT  = ws;                          // BB*HH*NN f32
    float* Eb   = EaT + BB * NN * HH;          // BB*MM*HH f32
    float* psum = Eb + BB * MM * HH;           // 16*BB*NN f32
    __half* Ph    = (__half*)(psum + 16 * BB * NN);   // BB*NN*MM f16
    __half* KT_hi = Ph + (size_t)BB * NN * MM;        // BB*DD*MM f16
    __half* KT_lo = KT_hi + (size_t)BB * DD * MM;     // BB*DD*MM f16
    float* partial = (float*)(KT_lo + (size_t)BB * DD * MM);  // 2*BB*NN*DD f32

    proj_conv_kernel<<<dim3(512 + 128), dim3(256), 0, stream>>>(
        query, key, Wa_w, Wa_b, Wb_w, Wb_b, EaT, Eb, KT_hi, KT_lo);
    scores_kernel<<<dim3(MM / 128, NN / 32, BB), dim3(256), 0, stream>>>(
        EaT, Eb, v_w, Ph, psum);
    attend_kernel<<<dim3(256), dim3(512), 0, stream>>>(
        Ph, KT_hi, KT_lo, partial);
    combine_kernel<<<dim3(NN, BB), dim3(256), 0, stream>>>(
        partial, psum, out);
}

// Round 15
// 58.309 us; speedup vs baseline: 3.5599x; 1.0522x over previous
//
#include <hip/hip_runtime.h>
#include <hip/hip_fp16.h>

#define BB 2
#define NN 1024
#define MM 1024
#define DD 256
#define HH 128
#define C2LE 2.8853900817779268f       // 2*log2(e)
#define NEG2LOG2E -2.8853900817779268f // -2*log2(e)
#define SHIFT_C -4.3280860f            // -3*log2(e): P = e^{s-3}, softmax-invariant

typedef float v2f __attribute__((ext_vector_type(2)));
typedef float v4f __attribute__((ext_vector_type(4)));
typedef _Float16 h8 __attribute__((ext_vector_type(8)));

// ---- Kernel 1: blocks <512: e = exp2(C*(x@W+bias)) -> EaT (A, transposed) /
// Eb (B, row-major). blocks >=512: KT_hi[b][d][m] = f16(key^T).
__global__ __launch_bounds__(256) void proj_conv_kernel(
    const float* __restrict__ query, const float* __restrict__ key,
    const float* __restrict__ Wa_w, const float* __restrict__ Wa_b,
    const float* __restrict__ Wb_w, const float* __restrict__ Wb_b,
    float* __restrict__ EaT, float* __restrict__ Eb,
    __half* __restrict__ KT_hi) {
    __shared__ float rows[8][DD];
    __shared__ float partial[8][HH];
    __shared__ float t[64][65];
    const int tid = threadIdx.x;

    if (blockIdx.x >= 512) {  // ---- convert branch
        const int cid = blockIdx.x - 512;
        const int m0 = (cid & 15) * 64, d0 = ((cid >> 4) & 3) * 64, b = cid >> 6;
        for (int i = tid; i < 1024; i += 256) {
            const int r = i >> 4, c4 = i & 15;
            const float4 v =
                *(const float4*)&key[((size_t)(b * MM + m0 + r)) * DD + d0 + c4 * 4];
            t[r][c4 * 4 + 0] = v.x; t[r][c4 * 4 + 1] = v.y;
            t[r][c4 * 4 + 2] = v.z; t[r][c4 * 4 + 3] = v.w;
        }
        __syncthreads();
        for (int i = tid; i < 4096; i += 256) {
            const int dr = i >> 6, mc = i & 63;
            KT_hi[((size_t)(b * DD + d0 + dr)) * MM + m0 + mc] =
                __float2half(t[mc][dr]);
        }
        return;
    }

    const int rb = blockIdx.x * 8;
    const bool isA = rb < BB * NN;
    const float* in = isA ? query : key;
    const float* W  = isA ? Wa_w : Wb_w;
    const float* bias = isA ? Wa_b : Wb_b;
    const int base = isA ? rb : rb - BB * NN;

    const float4* in4 = (const float4*)(in + (size_t)base * DD);
    float4* rows4 = (float4*)rows;
    rows4[tid] = in4[tid];
    rows4[tid + 256] = in4[tid + 256];
    __syncthreads();

    const int h = tid & 127, half = tid >> 7;
    const int d0 = half * 128;
    float acc[8] = {};
    for (int d = d0; d < d0 + 128; d += 4) {
        const float w0 = W[(d + 0) * HH + h];
        const float w1 = W[(d + 1) * HH + h];
        const float w2 = W[(d + 2) * HH + h];
        const float w3 = W[(d + 3) * HH + h];
#pragma unroll
        for (int r = 0; r < 8; ++r) {
            const float4 rv = *(const float4*)&rows[r][d];
            acc[r] = fmaf(rv.x, w0, fmaf(rv.y, w1, fmaf(rv.z, w2, fmaf(rv.w, w3, acc[r]))));
        }
    }
    if (half) {
#pragma unroll
        for (int r = 0; r < 8; ++r) partial[r][h] = acc[r];
    }
    __syncthreads();
    if (!half) {
        const float bv = bias[h];
        float ev[8];
#pragma unroll
        for (int r = 0; r < 8; ++r)
            ev[r] = __builtin_amdgcn_exp2f(C2LE * (acc[r] + partial[r][h] + bv));
        if (isA) {
            const int bq = base >> 10, nb = base & (NN - 1);
            float* dst = EaT + ((size_t)(bq * HH + h)) * NN + nb;
            *(float4*)dst = *(float4*)&ev[0];
            *(float4*)(dst + 4) = *(float4*)&ev[4];
        } else {
#pragma unroll
            for (int r = 0; r < 8; ++r)
                Eb[(size_t)(base + r) * HH + h] = ev[r];
        }
    }
}

// ---- Kernel 2 v2: Ph = f16(exp(-2*sum_h v_h/(Ea*Eb+1) - 3)) + psum.
// Tile 32n x 128m (mt=2 per lane), h in 2 chunks of 64.
__global__ __launch_bounds__(256) void scores_kernel(
    const float* __restrict__ EaT, const float* __restrict__ Eb,
    const float* __restrict__ v_w, __half* __restrict__ Ph,
    float* __restrict__ psum) {
    __shared__ float b_s[128 * 64];  // 32KB, swizzled: slot = h4 ^ (r&15)
    __shared__ float a_s[64 * 32];   // 8KB, [h][n]
    const int tid = threadIdx.x;
    const int m0 = blockIdx.x * 128, n0 = blockIdx.y * 32, b = blockIdx.z;
    const int lane = tid & 63;
    const int ng = __builtin_amdgcn_readfirstlane(threadIdx.x >> 6);
    const int skey = lane & 15;

    v2f acc[2][4] = {};  // [mt][np]
    for (int hc = 0; hc < 2; ++hc) {
        __syncthreads();
        for (int i = tid; i < 128 * 16; i += 256) {
            const int r = i >> 4, h4 = i & 15;
            *(float4*)&b_s[r * 64 + ((h4 ^ (r & 15)) << 2)] =
                *(const float4*)&Eb[((size_t)(b * MM + m0 + r)) * HH + hc * 64 + h4 * 4];
        }
        for (int i = tid; i < 64 * 8; i += 256) {
            const int hh = i >> 3, n4 = i & 7;
            *(float4*)&a_s[hh * 32 + n4 * 4] =
                *(const float4*)&EaT[((size_t)(b * HH + hc * 64 + hh)) * NN + n0 + n4 * 4];
        }
        __syncthreads();

#pragma unroll 4
        for (int h4 = 0; h4 < 16; ++h4) {
            const float4 w4 = *(const float4*)&v_w[hc * 64 + h4 * 4];  // uniform
            const float* ap = &a_s[h4 * 4 * 32 + ng * 8];
            v2f A0[4], A1[4], A2[4], A3[4];
#pragma unroll
            for (int np = 0; np < 4; ++np) {
                A0[np] = *(const v2f*)&ap[0 * 32 + np * 2];
                A1[np] = *(const v2f*)&ap[1 * 32 + np * 2];
                A2[np] = *(const v2f*)&ap[2 * 32 + np * 2];
                A3[np] = *(const v2f*)&ap[3 * 32 + np * 2];
            }
#pragma unroll
            for (int mt = 0; mt < 2; ++mt) {
                const float4 b4 = *(const float4*)
                    &b_s[(mt * 64 + lane) * 64 + ((h4 ^ skey) << 2)];
#pragma unroll
                for (int np = 0; np < 4; ++np) {
                    const v2f u0 = A0[np] * b4.x + 1.0f;
                    const v2f u1 = A1[np] * b4.y + 1.0f;
                    const v2f u2 = A2[np] * b4.z + 1.0f;
                    const v2f u3 = A3[np] * b4.w + 1.0f;
                    const v2f p01 = u0 * u1, p23 = u2 * u3;
                    const v2f An = w4.x * u1 + w4.y * u0;
                    const v2f Bn = w4.z * u3 + w4.w * u2;
                    const v2f num = An * p23 + Bn * p01;
                    const v2f Pp = p01 * p23;
                    v2f r2;
                    r2.x = __builtin_amdgcn_rcpf(Pp.x);
                    r2.y = __builtin_amdgcn_rcpf(Pp.y);
                    acc[mt][np] = num * r2 + acc[mt][np];
                }
            }
        }
    }

    const size_t prow = ((size_t)b * NN + n0 + ng * 8) * MM + m0 + lane;
#pragma unroll
    for (int j = 0; j < 8; ++j) {
#pragma unroll
        for (int mt = 0; mt < 2; ++mt) {
            const float pv = __builtin_amdgcn_exp2f(
                fmaf(acc[mt][j >> 1][j & 1], NEG2LOG2E, SHIFT_C));
            Ph[prow + (size_t)j * MM + mt * 64] = __float2half(pv);
            float s = pv;
#pragma unroll
            for (int o = 32; o > 0; o >>= 1) s += __shfl_xor(s, o);
            if (lane == 0)
                psum[((size_t)(m0 / 64 + mt) * BB + b) * NN + n0 + ng * 8 + j] = s;
        }
    }
}

// ---- Kernel 3 v5: LDS-staged MFMA GEMM with RAW barriers (no vmcnt drain).
// Block 64n x 64d, k-split 4 (m0=ks*256), 4 k-steps of 64. Prefetched global
// loads stay in flight across s_barrier (only lgkmcnt(0) is waited).
__global__ __launch_bounds__(512) void attend_kernel(
    const __half* __restrict__ Ph, const __half* __restrict__ KT_hi,
    float* __restrict__ partial) {
    __shared__ __align__(16) __half Ab[2][4096];  // 8KB x2
    __shared__ __align__(16) __half Bh[2][4096];  // 8KB x2

    const int bid = blockIdx.x;
    const int xcd = bid & 7, idx = bid >> 3;
    const int b = idx & 1, ks = (idx >> 1) & 3, dt = (idx >> 3) & 3;
    const int nt = xcd * 2 + ((idx >> 5) & 1);
    const int n0 = nt * 64, d0 = dt * 64, m0 = ks * 256;

    const int tid = threadIdx.x;
    const int lane = tid & 63;
    // staging decomposition: tid -> (st, skh, skg, srow); LDS off = tid*8
    const int srow = tid & 15, skg = (tid >> 4) & 3;
    const int ssub = tid >> 6, skh = ssub & 1, st = ssub >> 1;
    const int scol = m0 + skh * 32 + skg * 8;

    const __half* srcA = Ph    + ((size_t)(b * NN + n0 + st * 16 + srow)) * MM + scol;
    const __half* srcB = KT_hi + ((size_t)(b * DD + d0 + st * 16 + srow)) * MM + scol;

    const int wave = __builtin_amdgcn_readfirstlane(threadIdx.x >> 6);
    const int t0 = (wave >> 2) * 2, td = wave & 3;

    v4f c0 = {0.f, 0.f, 0.f, 0.f}, c1 = c0;

    h8 ra = *(const h8*)srcA;  // step-0 loads
    h8 rb = *(const h8*)srcB;

    int cur = 0;
#pragma unroll 1
    for (int step = 0; step < 4; ++step) {
        *(h8*)&Ab[cur][tid * 8] = ra;   // vmcnt dep waits only these regs
        *(h8*)&Bh[cur][tid * 8] = rb;
        if (step < 3) {                 // issue next loads; stay in flight
            ra = *(const h8*)(srcA + (step + 1) * 64);
            rb = *(const h8*)(srcB + (step + 1) * 64);
        }
        asm volatile("s_waitcnt lgkmcnt(0)" ::: "memory");  // ds_writes visible
        __builtin_amdgcn_sched_barrier(0);
        __builtin_amdgcn_s_barrier();   // RAW barrier: no vmcnt(0) drain

        const __half* A = Ab[cur];
        const __half* B = Bh[cur];
        const h8 a00 = *(const h8*)&A[((t0 * 2 + 0) * 64 + lane) * 8];
        const h8 a01 = *(const h8*)&A[((t0 * 2 + 1) * 64 + lane) * 8];
        const h8 a10 = *(const h8*)&A[((t0 * 2 + 2) * 64 + lane) * 8];
        const h8 a11 = *(const h8*)&A[((t0 * 2 + 3) * 64 + lane) * 8];
        const h8 b0  = *(const h8*)&B[((td * 2 + 0) * 64 + lane) * 8];
        const h8 b1  = *(const h8*)&B[((td * 2 + 1) * 64 + lane) * 8];
        c0 = __builtin_amdgcn_mfma_f32_16x16x32_f16(a00, b0, c0, 0, 0, 0);
        c0 = __builtin_amdgcn_mfma_f32_16x16x32_f16(a01, b1, c0, 0, 0, 0);
        c1 = __builtin_amdgcn_mfma_f32_16x16x32_f16(a10, b0, c1, 0, 0, 0);
        c1 = __builtin_amdgcn_mfma_f32_16x16x32_f16(a11, b1, c1, 0, 0, 0);
        cur ^= 1;
    }

    const int row16 = lane & 15, kg = lane >> 4;
    float* pp0 = partial +
        (((size_t)ks * BB + b) * NN + n0 + t0 * 16 + kg * 4) * DD + d0 + td * 16 + row16;
    float* pp1 = pp0 + (size_t)16 * DD;
#pragma unroll
    for (int r = 0; r < 4; ++r) pp0[(size_t)r * DD] = c0[r];
#pragma unroll
    for (int r = 0; r < 4; ++r) pp1[(size_t)r * DD] = c1[r];
}

// ---- Kernel 4: out[b,n,d] = sum_ks partial / sum_q psum[q][b][n]
__global__ __launch_bounds__(256) void combine_kernel(
    const float* __restrict__ partial, const float* __restrict__ psum,
    float* __restrict__ out) {
    const int n = blockIdx.x, b = blockIdx.y, d = threadIdx.x;
    float s = 0.f;
#pragma unroll
    for (int q = 0; q < 16; ++q)
        s += psum[((size_t)q * BB + b) * NN + n];
    const size_t off = ((size_t)b * NN + n) * DD + d;
    float a = 0.f;
#pragma unroll
    for (int ks = 0; ks < 4; ++ks)
        a += partial[((size_t)ks * BB) * NN * DD + off];
    out[off] = a * __builtin_amdgcn_rcpf(s);
}

extern "C" void kernel_launch(void* const* d_in, const int* in_sizes, int n_in,
                              void* d_out, int out_size, void* d_ws, size_t ws_size,
                              hipStream_t stream) {
    const float* query = (const float*)d_in[0];
    const float* key   = (const float*)d_in[1];
    const float* Wa_w  = (const float*)d_in[2];
    const float* Wa_b  = (const float*)d_in[3];
    const float* Wb_w  = (const float*)d_in[4];
    const float* Wb_b  = (const float*)d_in[5];
    const float* v_w   = (const float*)d_in[6];
    float* out = (float*)d_out;

    float* ws = (float*)d_ws;
    float* EaT  = ws;                          // BB*HH*NN f32
    float* Eb   = EaT + BB * NN * HH;          // BB*MM*HH f32
    float* psum = Eb + BB * MM * HH;           // 16*BB*NN f32
    __half* Ph    = (__half*)(psum + 16 * BB * NN);   // BB*NN*MM f16
    __half* KT_hi = Ph + (size_t)BB * NN * MM;        // BB*DD*MM f16
    float* partial = (float*)(KT_hi + (size_t)BB * DD * MM);  // 4*BB*NN*DD f32

    proj_conv_kernel<<<dim3(512 + 128), dim3(256), 0, stream>>>(
        query, key, Wa_w, Wa_b, Wb_w, Wb_b, EaT, Eb, KT_hi);
    scores_kernel<<<dim3(MM / 128, NN / 32, BB), dim3(256), 0, stream>>>(
        EaT, Eb, v_w, Ph, psum);
    attend_kernel<<<dim3(512), dim3(512), 0, stream>>>(
        Ph, KT_hi, partial);
    combine_kernel<<<dim3(NN, BB), dim3(256), 0, stream>>>(
        partial, psum, out);
}

// Round 16
// 57.139 us; speedup vs baseline: 3.6328x; 1.0205x over previous
//
#include <hip/hip_runtime.h>
#include <hip/hip_fp16.h>

#define BB 2
#define NN 1024
#define MM 1024
#define DD 256
#define HH 128
#define C2LE 2.8853900817779268f       // 2*log2(e)
#define NEG2LOG2E -2.8853900817779268f // -2*log2(e)
#define SHIFT_C -4.3280860f            // -3*log2(e): P = e^{s-3}, softmax-invariant

typedef float v2f __attribute__((ext_vector_type(2)));
typedef float v4f __attribute__((ext_vector_type(4)));
typedef _Float16 h8 __attribute__((ext_vector_type(8)));

// ---- Kernel 1: blocks <512: e = exp2(C*(x@W+bias)) -> EaT (A, transposed) /
// Eb (B, row-major). blocks >=512: KT_hi[b][d][m] = f16(key^T).
__global__ __launch_bounds__(256) void proj_conv_kernel(
    const float* __restrict__ query, const float* __restrict__ key,
    const float* __restrict__ Wa_w, const float* __restrict__ Wa_b,
    const float* __restrict__ Wb_w, const float* __restrict__ Wb_b,
    float* __restrict__ EaT, float* __restrict__ Eb,
    __half* __restrict__ KT_hi) {
    __shared__ float rows[8][DD];
    __shared__ float partial[8][HH];
    __shared__ float t[64][65];
    const int tid = threadIdx.x;

    if (blockIdx.x >= 512) {  // ---- convert branch
        const int cid = blockIdx.x - 512;
        const int m0 = (cid & 15) * 64, d0 = ((cid >> 4) & 3) * 64, b = cid >> 6;
        for (int i = tid; i < 1024; i += 256) {
            const int r = i >> 4, c4 = i & 15;
            const float4 v =
                *(const float4*)&key[((size_t)(b * MM + m0 + r)) * DD + d0 + c4 * 4];
            t[r][c4 * 4 + 0] = v.x; t[r][c4 * 4 + 1] = v.y;
            t[r][c4 * 4 + 2] = v.z; t[r][c4 * 4 + 3] = v.w;
        }
        __syncthreads();
        for (int i = tid; i < 4096; i += 256) {
            const int dr = i >> 6, mc = i & 63;
            KT_hi[((size_t)(b * DD + d0 + dr)) * MM + m0 + mc] =
                __float2half(t[mc][dr]);
        }
        return;
    }

    const int rb = blockIdx.x * 8;
    const bool isA = rb < BB * NN;
    const float* in = isA ? query : key;
    const float* W  = isA ? Wa_w : Wb_w;
    const float* bias = isA ? Wa_b : Wb_b;
    const int base = isA ? rb : rb - BB * NN;

    const float4* in4 = (const float4*)(in + (size_t)base * DD);
    float4* rows4 = (float4*)rows;
    rows4[tid] = in4[tid];
    rows4[tid + 256] = in4[tid + 256];
    __syncthreads();

    const int h = tid & 127, half = tid >> 7;
    const int d0 = half * 128;
    float acc[8] = {};
    for (int d = d0; d < d0 + 128; d += 4) {
        const float w0 = W[(d + 0) * HH + h];
        const float w1 = W[(d + 1) * HH + h];
        const float w2 = W[(d + 2) * HH + h];
        const float w3 = W[(d + 3) * HH + h];
#pragma unroll
        for (int r = 0; r < 8; ++r) {
            const float4 rv = *(const float4*)&rows[r][d];
            acc[r] = fmaf(rv.x, w0, fmaf(rv.y, w1, fmaf(rv.z, w2, fmaf(rv.w, w3, acc[r]))));
        }
    }
    if (half) {
#pragma unroll
        for (int r = 0; r < 8; ++r) partial[r][h] = acc[r];
    }
    __syncthreads();
    if (!half) {
        const float bv = bias[h];
        float ev[8];
#pragma unroll
        for (int r = 0; r < 8; ++r)
            ev[r] = __builtin_amdgcn_exp2f(C2LE * (acc[r] + partial[r][h] + bv));
        if (isA) {
            const int bq = base >> 10, nb = base & (NN - 1);
            float* dst = EaT + ((size_t)(bq * HH + h)) * NN + nb;
            *(float4*)dst = *(float4*)&ev[0];
            *(float4*)(dst + 4) = *(float4*)&ev[4];
        } else {
#pragma unroll
            for (int r = 0; r < 8; ++r)
                Eb[(size_t)(base + r) * HH + h] = ev[r];
        }
    }
}

// ---- Kernel 2 v2: Ph = f16(exp(-2*sum_h v_h/(Ea*Eb+1) - 3)) + psum.
// Tile 32n x 128m (mt=2 per lane), h in 2 chunks of 64.
__global__ __launch_bounds__(256) void scores_kernel(
    const float* __restrict__ EaT, const float* __restrict__ Eb,
    const float* __restrict__ v_w, __half* __restrict__ Ph,
    float* __restrict__ psum) {
    __shared__ float b_s[128 * 64];  // 32KB, swizzled: slot = h4 ^ (r&15)
    __shared__ float a_s[64 * 32];   // 8KB, [h][n]
    const int tid = threadIdx.x;
    const int m0 = blockIdx.x * 128, n0 = blockIdx.y * 32, b = blockIdx.z;
    const int lane = tid & 63;
    const int ng = __builtin_amdgcn_readfirstlane(threadIdx.x >> 6);
    const int skey = lane & 15;

    v2f acc[2][4] = {};  // [mt][np]
    for (int hc = 0; hc < 2; ++hc) {
        __syncthreads();
        for (int i = tid; i < 128 * 16; i += 256) {
            const int r = i >> 4, h4 = i & 15;
            *(float4*)&b_s[r * 64 + ((h4 ^ (r & 15)) << 2)] =
                *(const float4*)&Eb[((size_t)(b * MM + m0 + r)) * HH + hc * 64 + h4 * 4];
        }
        for (int i = tid; i < 64 * 8; i += 256) {
            const int hh = i >> 3, n4 = i & 7;
            *(float4*)&a_s[hh * 32 + n4 * 4] =
                *(const float4*)&EaT[((size_t)(b * HH + hc * 64 + hh)) * NN + n0 + n4 * 4];
        }
        __syncthreads();

#pragma unroll 4
        for (int h4 = 0; h4 < 16; ++h4) {
            const float4 w4 = *(const float4*)&v_w[hc * 64 + h4 * 4];  // uniform
            const float* ap = &a_s[h4 * 4 * 32 + ng * 8];
            v2f A0[4], A1[4], A2[4], A3[4];
#pragma unroll
            for (int np = 0; np < 4; ++np) {
                A0[np] = *(const v2f*)&ap[0 * 32 + np * 2];
                A1[np] = *(const v2f*)&ap[1 * 32 + np * 2];
                A2[np] = *(const v2f*)&ap[2 * 32 + np * 2];
                A3[np] = *(const v2f*)&ap[3 * 32 + np * 2];
            }
#pragma unroll
            for (int mt = 0; mt < 2; ++mt) {
                const float4 b4 = *(const float4*)
                    &b_s[(mt * 64 + lane) * 64 + ((h4 ^ skey) << 2)];
#pragma unroll
                for (int np = 0; np < 4; ++np) {
                    const v2f u0 = A0[np] * b4.x + 1.0f;
                    const v2f u1 = A1[np] * b4.y + 1.0f;
                    const v2f u2 = A2[np] * b4.z + 1.0f;
                    const v2f u3 = A3[np] * b4.w + 1.0f;
                    const v2f p01 = u0 * u1, p23 = u2 * u3;
                    const v2f An = w4.x * u1 + w4.y * u0;
                    const v2f Bn = w4.z * u3 + w4.w * u2;
                    const v2f num = An * p23 + Bn * p01;
                    const v2f Pp = p01 * p23;
                    v2f r2;
                    r2.x = __builtin_amdgcn_rcpf(Pp.x);
                    r2.y = __builtin_amdgcn_rcpf(Pp.y);
                    acc[mt][np] = num * r2 + acc[mt][np];
                }
            }
        }
    }

    const size_t prow = ((size_t)b * NN + n0 + ng * 8) * MM + m0 + lane;
#pragma unroll
    for (int j = 0; j < 8; ++j) {
#pragma unroll
        for (int mt = 0; mt < 2; ++mt) {
            const float pv = __builtin_amdgcn_exp2f(
                fmaf(acc[mt][j >> 1][j & 1], NEG2LOG2E, SHIFT_C));
            Ph[prow + (size_t)j * MM + mt * 64] = __float2half(pv);
            float s = pv;
#pragma unroll
            for (int o = 32; o > 0; o >>= 1) s += __shfl_xor(s, o);
            if (lane == 0)
                psum[((size_t)(m0 / 64 + mt) * BB + b) * NN + n0 + ng * 8 + j] = s;
        }
    }
}

// ---- Kernel 3 v6: full-k LDS-staged MFMA GEMM, normalize fused, direct out.
// Block 32n x 64d, 8 waves = 2x4 (16n x 16d) tiles, 16 k-steps of 64.
// Raw barriers (lgkmcnt only) keep prefetch in flight; bid&7 groups the 8
// (dt,b) combos per XCD so each XCD's KT slice stays L2-resident.
__global__ __launch_bounds__(512) void attend_kernel(
    const __half* __restrict__ Ph, const __half* __restrict__ KT_hi,
    const float* __restrict__ psum, float* __restrict__ out) {
    __shared__ __align__(16) __half Ab[2][4 * 512];  // 4KB x2
    __shared__ __align__(16) __half Bb[2][8 * 512];  // 8KB x2
    __shared__ float inv[32];

    const int bid = blockIdx.x;
    const int g = bid & 7, nt = bid >> 3;  // (dt,b) per XCD; nt sweeps n
    const int dt = g >> 1, b = g & 1;
    const int n0 = nt * 32, d0 = dt * 64;

    const int tid = threadIdx.x;
    const int lane = tid & 63;
    const int row16 = lane & 15, kg = lane >> 4;

    if (tid < 32) {
        float s = 0.f;
#pragma unroll
        for (int q = 0; q < 16; ++q)
            s += psum[((size_t)q * BB + b) * NN + n0 + tid];
        inv[tid] = __builtin_amdgcn_rcpf(s);
    }

    // staging: B chunk cb=0..7 -> (sd=cb>>1, skh=cb&1); A chunk ca=0..3 (tid<256)
    const int cb = tid >> 6;
    const int sdB = cb >> 1, skhB = cb & 1;
    const __half* srcB = KT_hi +
        ((size_t)(b * DD + d0 + sdB * 16 + row16)) * MM + skhB * 32 + kg * 8;
    const bool hasA = tid < 256;
    const int ca = cb & 3;
    const int snA = ca >> 1, skhA = ca & 1;
    const __half* srcA = Ph +
        ((size_t)(b * NN + n0 + snA * 16 + row16)) * MM + skhA * 32 + kg * 8;

    const int wave = __builtin_amdgcn_readfirstlane(threadIdx.x >> 6);
    const int t = wave >> 2, td = wave & 3;

    v4f c = {0.f, 0.f, 0.f, 0.f};

    h8 rb = *(const h8*)srcB;
    h8 ra;
    if (hasA) ra = *(const h8*)srcA;

    int cur = 0;
#pragma unroll 1
    for (int step = 0; step < 16; ++step) {
        *(h8*)&Bb[cur][cb * 512 + lane * 8] = rb;
        if (hasA) *(h8*)&Ab[cur][ca * 512 + lane * 8] = ra;
        if (step < 15) {  // issue next-step loads; stay in flight across barrier
            rb = *(const h8*)(srcB + (step + 1) * 64);
            if (hasA) ra = *(const h8*)(srcA + (step + 1) * 64);
        }
        asm volatile("s_waitcnt lgkmcnt(0)" ::: "memory");  // ds_writes visible
        __builtin_amdgcn_sched_barrier(0);
        __builtin_amdgcn_s_barrier();  // raw barrier: no vmcnt(0) drain

        const h8 a0 = *(const h8*)&Ab[cur][(t * 2 + 0) * 512 + lane * 8];
        const h8 a1 = *(const h8*)&Ab[cur][(t * 2 + 1) * 512 + lane * 8];
        const h8 b0 = *(const h8*)&Bb[cur][(td * 2 + 0) * 512 + lane * 8];
        const h8 b1 = *(const h8*)&Bb[cur][(td * 2 + 1) * 512 + lane * 8];
        c = __builtin_amdgcn_mfma_f32_16x16x32_f16(a0, b0, c, 0, 0, 0);
        c = __builtin_amdgcn_mfma_f32_16x16x32_f16(a1, b1, c, 0, 0, 0);
        cur ^= 1;
    }

    const int nloc = t * 16 + kg * 4;
    float* po = out + ((size_t)(b * NN + n0 + nloc)) * DD + d0 + td * 16 + row16;
#pragma unroll
    for (int r = 0; r < 4; ++r)
        po[(size_t)r * DD] = c[r] * inv[nloc + r];
}

extern "C" void kernel_launch(void* const* d_in, const int* in_sizes, int n_in,
                              void* d_out, int out_size, void* d_ws, size_t ws_size,
                              hipStream_t stream) {
    const float* query = (const float*)d_in[0];
    const float* key   = (const float*)d_in[1];
    const float* Wa_w  = (const float*)d_in[2];
    const float* Wa_b  = (const float*)d_in[3];
    const float* Wb_w  = (const float*)d_in[4];
    const float* Wb_b  = (const float*)d_in[5];
    const float* v_w   = (const float*)d_in[6];
    float* out = (float*)d_out;

    float* ws = (float*)d_ws;
    float* EaT  = ws;                          // BB*HH*NN f32
    float* Eb   = EaT + BB * NN * HH;          // BB*MM*HH f32
    float* psum = Eb + BB * MM * HH;           // 16*BB*NN f32
    __half* Ph    = (__half*)(psum + 16 * BB * NN);   // BB*NN*MM f16
    __half* KT_hi = Ph + (size_t)BB * NN * MM;        // BB*DD*MM f16

    proj_conv_kernel<<<dim3(512 + 128), dim3(256), 0, stream>>>(
        query, key, Wa_w, Wa_b, Wb_w, Wb_b, EaT, Eb, KT_hi);
    scores_kernel<<<dim3(MM / 128, NN / 32, BB), dim3(256), 0, stream>>>(
        EaT, Eb, v_w, Ph, psum);
    attend_kernel<<<dim3(256), dim3(512), 0, stream>>>(
        Ph, KT_hi, psum, out);
}